// Round 1
// 719.694 us; speedup vs baseline: 1.0202x; 1.0202x over previous
//
#include <hip/hip_runtime.h>

#define N_NODES 50000
#define N_EDGES 1600000
#define R_WAV 4
#define D 128
#define NB 391                 // ceil(50000/128) buckets of 128 rows
#define CHUNK 4096             // edges per hist/partition block
#define NPBLK ((N_EDGES + CHUNK - 1) / CHUNK)   // 391
#define MAXB 4800              // bucket capacity for LDS sort (mean 4092, sigma 64)
#define RP_STRIDE 50016        // ints per row_ptr array (>= N+1), batched layout

typedef unsigned int u32;
typedef unsigned short u16;

// fp32 -> bf16 bits, round-to-nearest-even
static __device__ inline u16 f2bf(float f) {
    u32 u = __float_as_uint(f);
    u = (u + 0x7FFFu + ((u >> 16) & 1u)) >> 16;
    return (u16)u;
}
static __device__ inline float bf_lo(u32 u) { return __uint_as_float(u << 16); }
static __device__ inline float bf_hi(u32 u) { return __uint_as_float(u & 0xFFFF0000u); }

// ---------------- GEMM: h = x @ W, bf16 row-major [N][128] -------------------
// 16 rows per block: x reads are wave-uniform (scalar path), W re-read 4x less.
// Per-output k-order identical to previous version (numerics unchanged).
__global__ __launch_bounds__(128) void gemm_xw(const float* __restrict__ x,
                                               const float* __restrict__ W,
                                               u16* __restrict__ h) {
    const int j = threadIdx.x;
    const int row0 = blockIdx.x * 16;
    const float* xr = x + (size_t)row0 * D;
    float acc[16];
#pragma unroll
    for (int r = 0; r < 16; ++r) acc[r] = 0.f;
#pragma unroll 4
    for (int k = 0; k < 128; ++k) {
        const float w = W[k * D + j];
#pragma unroll
        for (int r = 0; r < 16; ++r) acc[r] += xr[r * D + k] * w;
    }
#pragma unroll
    for (int r = 0; r < 16; ++r) h[(size_t)(row0 + r) * D + j] = f2bf(acc[r]);
}

// ------------- batched bucket histogram: grid (NPBLK, R_WAV) -----------------
__global__ __launch_bounds__(256) void bucket_hist_all(const int* __restrict__ rows_all,
                                                       int* __restrict__ cnt4) {
    __shared__ int lh[NB];
    const int r = blockIdx.y;
    const int* rows = rows_all + (size_t)r * N_EDGES;
    int* cnt = cnt4 + r * NB;
    const int tid = threadIdx.x;
    for (int i = tid; i < NB; i += 256) lh[i] = 0;
    __syncthreads();
    const int e0 = blockIdx.x * CHUNK;
    const int e1 = min(e0 + CHUNK, N_EDGES);
    for (int i = e0 + tid; i < e1; i += 256) atomicAdd(&lh[rows[i] >> 7], 1);
    __syncthreads();
    for (int i = tid; i < NB; i += 256) {
        const int c = lh[i];
        if (c) atomicAdd(&cnt[i], c);
    }
}

// ------------- batched scan of bucket counts: grid R_WAV ---------------------
__global__ __launch_bounds__(512) void scan_buckets_all(const int* __restrict__ cnt4,
                                                        int* __restrict__ bptr4,
                                                        int* __restrict__ bcur4) {
    __shared__ int sa[512], sb[512];
    const int r = blockIdx.x;
    const int* cnt = cnt4 + r * NB;
    int* bptr = bptr4 + r * (NB + 1);
    int* bcur = bcur4 + r * NB;
    const int tid = threadIdx.x;
    const int v = (tid < NB) ? cnt[tid] : 0;
    sa[tid] = v;
    int* cur = sa;
    int* nxt = sb;
    for (int d = 1; d < 512; d <<= 1) {
        __syncthreads();
        int t = cur[tid];
        if (tid >= d) t += cur[tid - d];
        nxt[tid] = t;
        int* tmp = cur; cur = nxt; nxt = tmp;
    }
    __syncthreads();
    const int excl = cur[tid] - v;
    if (tid <= NB) bptr[tid] = excl;
    if (tid < NB) bcur[tid] = excl;
}

// ---------------- partition: LDS counting-sort chunks into bucket runs -------
// Batched over r via blockIdx.y (pass grid.y=1 + pre-offset pointers for the
// per-r fallback path).
__global__ __launch_bounds__(256) void partition_kernel(const int* __restrict__ rows,
                                                        const int* __restrict__ cols,
                                                        const float* __restrict__ vals,
                                                        int* __restrict__ bcur,
                                                        int2* __restrict__ cv) {
    const int r = blockIdx.y;
    rows += (size_t)r * N_EDGES;
    cols += (size_t)r * N_EDGES;
    vals += (size_t)r * N_EDGES;
    bcur += r * NB;
    cv   += (size_t)r * N_EDGES;
    __shared__ int lh[NB], lptr[NB], lcur[NB], lbase[NB];
    __shared__ int sa[256], sb[256];
    __shared__ int2 st[CHUNK];
    const int tid = threadIdx.x;
    for (int i = tid; i < NB; i += 256) lh[i] = 0;
    __syncthreads();
    const int e0 = blockIdx.x * CHUNK;
    const int e1 = min(e0 + CHUNK, N_EDGES);
    const int cnt = e1 - e0;
    for (int i = e0 + tid; i < e1; i += 256) atomicAdd(&lh[rows[i] >> 7], 1);
    __syncthreads();
    const int p0 = (2 * tid < NB) ? lh[2 * tid] : 0;
    const int p1 = (2 * tid + 1 < NB) ? lh[2 * tid + 1] : 0;
    sa[tid] = p0 + p1;
    int* cur = sa;
    int* nxt = sb;
    for (int d = 1; d < 256; d <<= 1) {
        __syncthreads();
        int t = cur[tid];
        if (tid >= d) t += cur[tid - d];
        nxt[tid] = t;
        int* tmp = cur; cur = nxt; nxt = tmp;
    }
    __syncthreads();
    const int pe = cur[tid] - (p0 + p1);
    if (2 * tid < NB)     { lptr[2 * tid] = pe;           lcur[2 * tid] = pe; }
    if (2 * tid + 1 < NB) { lptr[2 * tid + 1] = pe + p0;  lcur[2 * tid + 1] = pe + p0; }
    __syncthreads();
    for (int i = e0 + tid; i < e1; i += 256) {
        const int row = rows[i];
        const int b = row >> 7;
        const int pos = atomicAdd(&lcur[b], 1);
        st[pos] = make_int2((int)(((u32)row << 16) | (u32)cols[i]), __float_as_int(vals[i]));
    }
    __syncthreads();
    for (int b = tid; b < NB; b += 256) {
        const int c = lh[b];
        int gb = 0;
        if (c) gb = atomicAdd(&bcur[b], c);
        lbase[b] = gb - lptr[b];
    }
    __syncthreads();
    for (int i = tid; i < cnt; i += 256) {
        const int2 e = st[i];
        const int b = (int)((u32)e.x >> 23);
        cv[lbase[b] + i] = e;
    }
}

// ------- per-bucket CSR: 128-bin counting sort, emit packed 4B edges ---------
// cv4 entry: {bf16(val) : hi16, col : lo16}. Batched over r via blockIdx.y.
__global__ __launch_bounds__(256) void bucket_csr(const int* __restrict__ bptr,
                                                  const int2* __restrict__ cv,
                                                  u32* __restrict__ cv4,
                                                  int* __restrict__ row_ptr) {
    const int r = blockIdx.y;
    bptr    += r * (NB + 1);
    cv      += (size_t)r * N_EDGES;
    cv4     += (size_t)r * N_EDGES;
    row_ptr += r * RP_STRIDE;
    __shared__ int lh[128], lexcl[128], lcur[128];
    __shared__ u32 st[MAXB];
    const int b = blockIdx.x;
    const int s = bptr[b], e1 = bptr[b + 1];
    const int cnt = e1 - s;
    const int tid = threadIdx.x;
    if (tid < 128) lh[tid] = 0;
    __syncthreads();
    for (int i = s + tid; i < e1; i += 256)
        atomicAdd(&lh[((u32)cv[i].x >> 16) & 127u], 1);
    __syncthreads();
    if (tid < 64) {
        const int p0 = lh[2 * tid], p1 = lh[2 * tid + 1];
        int ssum = p0 + p1;
#pragma unroll
        for (int d = 1; d < 64; d <<= 1) {
            const int t = __shfl_up(ssum, d, 64);
            if (tid >= d) ssum += t;
        }
        const int pe = ssum - (p0 + p1);
        lexcl[2 * tid] = pe;          lcur[2 * tid] = pe;
        lexcl[2 * tid + 1] = pe + p0; lcur[2 * tid + 1] = pe + p0;
    }
    __syncthreads();
    for (int i = s + tid; i < e1; i += 256) {
        const int2 E = cv[i];
        const int lr = (int)(((u32)E.x >> 16) & 127u);
        const int pos = atomicAdd(&lcur[lr], 1);
        if (pos < MAXB)
            st[pos] = ((u32)f2bf(__int_as_float(E.y)) << 16) | ((u32)E.x & 0xFFFFu);
    }
    __syncthreads();
    const int wb = (cnt < MAXB) ? cnt : MAXB;
    for (int i = tid; i < wb; i += 256) cv4[s + i] = st[i];
    if (tid < 128) {
        const int row = (b << 7) + tid;
        if (row < N_NODES) row_ptr[row] = s + lexcl[tid];
    }
    if (blockIdx.x == 0 && tid == 0) row_ptr[N_NODES] = N_EDGES;
}

// ---------------- SpMM pass 1: y = bf16( filt * (A @ h) ) --------------------
// One wave per row; batched over r via blockIdx.y.
__global__ __launch_bounds__(256) void spmm1(const int* __restrict__ row_ptr,
                                             const u32* __restrict__ cvp,
                                             const u32* __restrict__ h2,
                                             const float* __restrict__ filt,
                                             u32* __restrict__ y2) {
    const int r = blockIdx.y;
    row_ptr += r * RP_STRIDE;
    cvp     += (size_t)r * N_EDGES;
    filt    += (size_t)r * N_NODES;
    y2      += (size_t)r * (N_NODES * 64);
    const int row = __builtin_amdgcn_readfirstlane(blockIdx.x * 4 + (threadIdx.x >> 6));
    const int lane = threadIdx.x & 63;
    const int half = lane >> 5;
    const int l = lane & 31;
    int e = row_ptr[row];
    const int end = row_ptr[row + 1];
    float a0 = 0.f, a1 = 0.f, a2 = 0.f, a3 = 0.f;
    float b0 = 0.f, b1 = 0.f, b2 = 0.f, b3 = 0.f;
    for (; e + 8 <= end; e += 8) {
        const u32 c0 = cvp[e], c1 = cvp[e + 1], c2 = cvp[e + 2], c3 = cvp[e + 3];
        const u32 c4 = cvp[e + 4], c5 = cvp[e + 5], c6 = cvp[e + 6], c7 = cvp[e + 7];
        const u32 uA = half ? c1 : c0;
        const u32 uB = half ? c3 : c2;
        const u32 uC = half ? c5 : c4;
        const u32 uD = half ? c7 : c6;
        const uint2 gA = *(const uint2*)(h2 + (uA & 0xFFFFu) * 64 + 2 * l);
        const uint2 gB = *(const uint2*)(h2 + (uB & 0xFFFFu) * 64 + 2 * l);
        const uint2 gC = *(const uint2*)(h2 + (uC & 0xFFFFu) * 64 + 2 * l);
        const uint2 gD = *(const uint2*)(h2 + (uD & 0xFFFFu) * 64 + 2 * l);
        const float vA = __uint_as_float(uA & 0xFFFF0000u);
        const float vB = __uint_as_float(uB & 0xFFFF0000u);
        const float vC = __uint_as_float(uC & 0xFFFF0000u);
        const float vD = __uint_as_float(uD & 0xFFFF0000u);
        a0 += vA * bf_lo(gA.x); a1 += vA * bf_hi(gA.x);
        a2 += vA * bf_lo(gA.y); a3 += vA * bf_hi(gA.y);
        b0 += vB * bf_lo(gB.x); b1 += vB * bf_hi(gB.x);
        b2 += vB * bf_lo(gB.y); b3 += vB * bf_hi(gB.y);
        a0 += vC * bf_lo(gC.x); a1 += vC * bf_hi(gC.x);
        a2 += vC * bf_lo(gC.y); a3 += vC * bf_hi(gC.y);
        b0 += vD * bf_lo(gD.x); b1 += vD * bf_hi(gD.x);
        b2 += vD * bf_lo(gD.y); b3 += vD * bf_hi(gD.y);
    }
    for (; e < end; e += 2) {
        const u32 c0 = cvp[e];
        const u32 c1 = (e + 1 < end) ? cvp[e + 1] : 0u;
        const u32 uA = half ? c1 : c0;
        const uint2 gA = *(const uint2*)(h2 + (uA & 0xFFFFu) * 64 + 2 * l);
        const float vA = __uint_as_float(uA & 0xFFFF0000u);
        a0 += vA * bf_lo(gA.x); a1 += vA * bf_hi(gA.x);
        a2 += vA * bf_lo(gA.y); a3 += vA * bf_hi(gA.y);
    }
    a0 += b0; a1 += b1; a2 += b2; a3 += b3;
    a0 += __shfl_xor(a0, 32, 64);
    a1 += __shfl_xor(a1, 32, 64);
    a2 += __shfl_xor(a2, 32, 64);
    a3 += __shfl_xor(a3, 32, 64);
    const float f = filt[row];
    if (half == 0) {
        uint2 o;
        o.x = (u32)f2bf(f * a0) | ((u32)f2bf(f * a1) << 16);
        o.y = (u32)f2bf(f * a2) | ((u32)f2bf(f * a3) << 16);
        *(uint2*)(y2 + (size_t)row * 64 + 2 * l) = o;
    }
}

// ------- SpMM pass 2 FUSED across r: out = bias + sum_r A_r @ y_r ------------
// Saves 3x read+write of the 25.6 MB fp32 out vs 4 sequential dispatches.
__global__ __launch_bounds__(256) void spmm2_fused(const int* __restrict__ rp_all,
                                                   const u32* __restrict__ cv4_all,
                                                   const u32* __restrict__ y2_all,
                                                   const float* __restrict__ bias,
                                                   float* __restrict__ out) {
    const int row = __builtin_amdgcn_readfirstlane(blockIdx.x * 4 + (threadIdx.x >> 6));
    const int lane = threadIdx.x & 63;
    const int half = lane >> 5;
    const int l = lane & 31;
    float a0 = 0.f, a1 = 0.f, a2 = 0.f, a3 = 0.f;
    float b0 = 0.f, b1 = 0.f, b2 = 0.f, b3 = 0.f;
    for (int r = 0; r < R_WAV; ++r) {
        const int* rp = rp_all + r * RP_STRIDE;
        const u32* cvp = cv4_all + (size_t)r * N_EDGES;
        const u32* y2 = y2_all + (size_t)r * (N_NODES * 64);
        int e = rp[row];
        const int end = rp[row + 1];
        for (; e + 8 <= end; e += 8) {
            const u32 c0 = cvp[e], c1 = cvp[e + 1], c2 = cvp[e + 2], c3 = cvp[e + 3];
            const u32 c4 = cvp[e + 4], c5 = cvp[e + 5], c6 = cvp[e + 6], c7 = cvp[e + 7];
            const u32 uA = half ? c1 : c0;
            const u32 uB = half ? c3 : c2;
            const u32 uC = half ? c5 : c4;
            const u32 uD = half ? c7 : c6;
            const uint2 gA = *(const uint2*)(y2 + (uA & 0xFFFFu) * 64 + 2 * l);
            const uint2 gB = *(const uint2*)(y2 + (uB & 0xFFFFu) * 64 + 2 * l);
            const uint2 gC = *(const uint2*)(y2 + (uC & 0xFFFFu) * 64 + 2 * l);
            const uint2 gD = *(const uint2*)(y2 + (uD & 0xFFFFu) * 64 + 2 * l);
            const float vA = __uint_as_float(uA & 0xFFFF0000u);
            const float vB = __uint_as_float(uB & 0xFFFF0000u);
            const float vC = __uint_as_float(uC & 0xFFFF0000u);
            const float vD = __uint_as_float(uD & 0xFFFF0000u);
            a0 += vA * bf_lo(gA.x); a1 += vA * bf_hi(gA.x);
            a2 += vA * bf_lo(gA.y); a3 += vA * bf_hi(gA.y);
            b0 += vB * bf_lo(gB.x); b1 += vB * bf_hi(gB.x);
            b2 += vB * bf_lo(gB.y); b3 += vB * bf_hi(gB.y);
            a0 += vC * bf_lo(gC.x); a1 += vC * bf_hi(gC.x);
            a2 += vC * bf_lo(gC.y); a3 += vC * bf_hi(gC.y);
            b0 += vD * bf_lo(gD.x); b1 += vD * bf_hi(gD.x);
            b2 += vD * bf_lo(gD.y); b3 += vD * bf_hi(gD.y);
        }
        for (; e < end; e += 2) {
            const u32 c0 = cvp[e];
            const u32 c1 = (e + 1 < end) ? cvp[e + 1] : 0u;
            const u32 uA = half ? c1 : c0;
            const uint2 gA = *(const uint2*)(y2 + (uA & 0xFFFFu) * 64 + 2 * l);
            const float vA = __uint_as_float(uA & 0xFFFF0000u);
            a0 += vA * bf_lo(gA.x); a1 += vA * bf_hi(gA.x);
            a2 += vA * bf_lo(gA.y); a3 += vA * bf_hi(gA.y);
        }
    }
    a0 += b0; a1 += b1; a2 += b2; a3 += b3;
    a0 += __shfl_xor(a0, 32, 64);
    a1 += __shfl_xor(a1, 32, 64);
    a2 += __shfl_xor(a2, 32, 64);
    a3 += __shfl_xor(a3, 32, 64);
    if (half == 0) {
        const float4 bb = *(const float4*)(bias + 4 * l);
        *(float4*)(out + (size_t)row * D + 4 * l) =
            make_float4(a0 + bb.x, a1 + bb.y, a2 + bb.z, a3 + bb.w);
    }
}

// ---------------- SpMM pass 2 (fallback per-r path) --------------------------
template <bool FIRST>
__global__ __launch_bounds__(256) void spmm2(const int* __restrict__ row_ptr,
                                             const u32* __restrict__ cvp,
                                             const u32* __restrict__ y2,
                                             const float* __restrict__ bias,
                                             float* __restrict__ out) {
    const int row = __builtin_amdgcn_readfirstlane(blockIdx.x * 4 + (threadIdx.x >> 6));
    const int lane = threadIdx.x & 63;
    const int half = lane >> 5;
    const int l = lane & 31;
    int e = row_ptr[row];
    const int end = row_ptr[row + 1];
    float a0 = 0.f, a1 = 0.f, a2 = 0.f, a3 = 0.f;
    float b0 = 0.f, b1 = 0.f, b2 = 0.f, b3 = 0.f;
    for (; e + 8 <= end; e += 8) {
        const u32 c0 = cvp[e], c1 = cvp[e + 1], c2 = cvp[e + 2], c3 = cvp[e + 3];
        const u32 c4 = cvp[e + 4], c5 = cvp[e + 5], c6 = cvp[e + 6], c7 = cvp[e + 7];
        const u32 uA = half ? c1 : c0;
        const u32 uB = half ? c3 : c2;
        const u32 uC = half ? c5 : c4;
        const u32 uD = half ? c7 : c6;
        const uint2 gA = *(const uint2*)(y2 + (uA & 0xFFFFu) * 64 + 2 * l);
        const uint2 gB = *(const uint2*)(y2 + (uB & 0xFFFFu) * 64 + 2 * l);
        const uint2 gC = *(const uint2*)(y2 + (uC & 0xFFFFu) * 64 + 2 * l);
        const uint2 gD = *(const uint2*)(y2 + (uD & 0xFFFFu) * 64 + 2 * l);
        const float vA = __uint_as_float(uA & 0xFFFF0000u);
        const float vB = __uint_as_float(uB & 0xFFFF0000u);
        const float vC = __uint_as_float(uC & 0xFFFF0000u);
        const float vD = __uint_as_float(uD & 0xFFFF0000u);
        a0 += vA * bf_lo(gA.x); a1 += vA * bf_hi(gA.x);
        a2 += vA * bf_lo(gA.y); a3 += vA * bf_hi(gA.y);
        b0 += vB * bf_lo(gB.x); b1 += vB * bf_hi(gB.x);
        b2 += vB * bf_lo(gB.y); b3 += vB * bf_hi(gB.y);
        a0 += vC * bf_lo(gC.x); a1 += vC * bf_hi(gC.x);
        a2 += vC * bf_lo(gC.y); a3 += vC * bf_hi(gC.y);
        b0 += vD * bf_lo(gD.x); b1 += vD * bf_hi(gD.x);
        b2 += vD * bf_lo(gD.y); b3 += vD * bf_hi(gD.y);
    }
    for (; e < end; e += 2) {
        const u32 c0 = cvp[e];
        const u32 c1 = (e + 1 < end) ? cvp[e + 1] : 0u;
        const u32 uA = half ? c1 : c0;
        const uint2 gA = *(const uint2*)(y2 + (uA & 0xFFFFu) * 64 + 2 * l);
        const float vA = __uint_as_float(uA & 0xFFFF0000u);
        a0 += vA * bf_lo(gA.x); a1 += vA * bf_hi(gA.x);
        a2 += vA * bf_lo(gA.y); a3 += vA * bf_hi(gA.y);
    }
    a0 += b0; a1 += b1; a2 += b2; a3 += b3;
    a0 += __shfl_xor(a0, 32, 64);
    a1 += __shfl_xor(a1, 32, 64);
    a2 += __shfl_xor(a2, 32, 64);
    a3 += __shfl_xor(a3, 32, 64);
    if (half == 0) {
        float* op = out + (size_t)row * D + 4 * l;
        if (FIRST) {
            const float4 bb = *(const float4*)(bias + 4 * l);
            *(float4*)op = make_float4(a0 + bb.x, a1 + bb.y, a2 + bb.z, a3 + bb.w);
        } else {
            const float4 cc = *(const float4*)op;
            *(float4*)op = make_float4(cc.x + a0, cc.y + a1, cc.z + a2, cc.w + a3);
        }
    }
}

extern "C" void kernel_launch(void* const* d_in, const int* in_sizes, int n_in,
                              void* d_out, int out_size, void* d_ws, size_t ws_size,
                              hipStream_t stream) {
    const float* x    = (const float*)d_in[0];  // [N,128]
    const float* vals = (const float*)d_in[1];  // [R,E]
    const float* W    = (const float*)d_in[2];  // [128,128]
    const float* filt = (const float*)d_in[3];  // [R*N,1]
    const float* bias = (const float*)d_in[4];  // [128]
    const int*   rows = (const int*)d_in[5];    // [R,E]
    const int*   cols = (const int*)d_in[6];    // [R,E]
    float* out = (float*)d_out;                 // [N,128]

    char* ws = (char*)d_ws;
    const size_t NEED_BATCHED = 90419968;       // ~90.4 MB batched layout

    if (ws_size >= NEED_BATCHED) {
        // Batched layout. cv8_all (part->csr) and y2_all (spmm1->spmm2) alias:
        // cv8 is fully consumed by bucket_csr before spmm1 writes y2.
        u16*  h   = (u16*)(ws);                 // 12,800,000 B bf16 [N][128]
        u32*  sh  = (u32*)(ws + 12800000);      // 51,200,000 B shared region
        int2* cv8 = (int2*)sh;                  //   as int2 [R][E]
        u32*  y2  = sh;                         //   as bf16 [R][N][128]
        u32*  cv4 = (u32*)(ws + 64000000);      // 25,600,000 B packed [R][E]
        int*  rp  = (int*)(ws + 89600000);      // 4 x RP_STRIDE ints
        int*  cnt4  = (int*)(ws + 90400512);
        int*  bptr4 = (int*)(ws + 90406912);
        int*  bcur4 = (int*)(ws + 90413312);

        gemm_xw<<<N_NODES / 16, 128, 0, stream>>>(x, W, h);

        hipMemsetAsync(cnt4, 0, 4 * NB * sizeof(int), stream);
        bucket_hist_all<<<dim3(NPBLK, R_WAV), 256, 0, stream>>>(rows, cnt4);
        scan_buckets_all<<<R_WAV, 512, 0, stream>>>(cnt4, bptr4, bcur4);

        partition_kernel<<<dim3(NPBLK, R_WAV), 256, 0, stream>>>(rows, cols, vals,
                                                                 bcur4, cv8);
        bucket_csr<<<dim3(NB, R_WAV), 256, 0, stream>>>(bptr4, cv8, cv4, rp);
        spmm1<<<dim3(N_NODES / 4, R_WAV), 256, 0, stream>>>(rp, cv4, (const u32*)h,
                                                            filt, y2);
        spmm2_fused<<<N_NODES / 4, 256, 0, stream>>>(rp, cv4, y2, bias, out);
    } else {
        // Fallback: proven per-r path (45 MB workspace).
        u16*  h       = (u16*)(ws);                    // 12,800,000 B
        u32*  y2      = (u32*)(ws + 12800000);         // 12,800,000 B
        int2* cv8     = (int2*)(ws + 25600000);        // 12,800,000 B
        u32*  cv4     = (u32*)(ws + 38400000);         //  6,400,512 B
        int*  row_ptr = (int*)(ws + 44800512);         //    200,064 B
        int*  cnt4    = (int*)(ws + 45000576);
        int*  bptr4   = (int*)(ws + 45006976);
        int*  bcur4   = (int*)(ws + 45013376);

        gemm_xw<<<N_NODES / 16, 128, 0, stream>>>(x, W, h);

        hipMemsetAsync(cnt4, 0, 4 * NB * sizeof(int), stream);
        bucket_hist_all<<<dim3(NPBLK, R_WAV), 256, 0, stream>>>(rows, cnt4);
        scan_buckets_all<<<R_WAV, 512, 0, stream>>>(cnt4, bptr4, bcur4);

        for (int r = 0; r < R_WAV; ++r) {
            const int*   rows_r = rows + (size_t)r * N_EDGES;
            const int*   cols_r = cols + (size_t)r * N_EDGES;
            const float* vals_r = vals + (size_t)r * N_EDGES;
            const float* filt_r = filt + (size_t)r * N_NODES;

            partition_kernel<<<dim3(NPBLK, 1), 256, 0, stream>>>(rows_r, cols_r, vals_r,
                                                                 bcur4 + r * NB, cv8);
            bucket_csr<<<dim3(NB, 1), 256, 0, stream>>>(bptr4 + r * (NB + 1), cv8,
                                                        cv4, row_ptr);
            spmm1<<<dim3(N_NODES / 4, 1), 256, 0, stream>>>(row_ptr, cv4, (const u32*)h,
                                                            filt_r, y2);
            if (r == 0)
                spmm2<true><<<N_NODES / 4, 256, 0, stream>>>(row_ptr, cv4, y2, bias, out);
            else
                spmm2<false><<<N_NODES / 4, 256, 0, stream>>>(row_ptr, cv4, y2, bias, out);
        }
    }
}